// Round 5
// baseline (162.593 us; speedup 1.0000x reference)
//
#include <hip/hip_runtime.h>
#include <hip/hip_bf16.h>
#include <stdint.h>

// VQ: inputs [32,512,256] f32, codebook [8192,256] f32.
// out = concat(quantized_st [4194304] f32, loss [1] f32)

#define NE   8192
#define DIM  256
#define NROW 16384
#define NELEM 4194304

typedef __attribute__((ext_vector_type(8))) short short8;
typedef __attribute__((ext_vector_type(4))) float f32x4;
typedef __attribute__((ext_vector_type(4))) unsigned short u16x4;

// workspace layout (bytes)
#define WS_X    0u           // bf16 inputs   8 MB
#define WS_CB   8388608u     // bf16 codebook 4 MB
#define WS_NORM 12582912u    // f32 norms     32 KB
#define WS_AMIN 12615680u    // u32 argmin keys [16384] (64 KB)
#define WS_PART 12681216u    // f32 loss partials [4096]

__device__ __forceinline__ unsigned short f2b(float f) {
  unsigned u = __float_as_uint(f);
  return (unsigned short)((u + 0x7fffu + ((u >> 16) & 1u)) >> 16);
}

__device__ __forceinline__ void async16(const void* g, void* l) {
  __builtin_amdgcn_global_load_lds(
      (const __attribute__((address_space(1))) void*)g,
      (__attribute__((address_space(3))) void*)l, 16, 0, 0);
}

// ---------------- prep: bf16 casts + code norms + init ----------------
__global__ void vq_prep(const float* __restrict__ x, const float* __restrict__ cb,
                        unsigned short* __restrict__ xb, unsigned short* __restrict__ cbb,
                        float* __restrict__ norms, unsigned* __restrict__ amin) {
  const int bid = blockIdx.x, tid = threadIdx.x;
  if (bid < 2048) {                       // inputs f32 -> bf16, 8 elems/thread
    const int i = (bid * 256 + tid) * 8;
    f32x4 v0 = *(const f32x4*)(x + i);
    f32x4 v1 = *(const f32x4*)(x + i + 4);
    short8 h;
    h[0] = (short)f2b(v0.x); h[1] = (short)f2b(v0.y);
    h[2] = (short)f2b(v0.z); h[3] = (short)f2b(v0.w);
    h[4] = (short)f2b(v1.x); h[5] = (short)f2b(v1.y);
    h[6] = (short)f2b(v1.z); h[7] = (short)f2b(v1.w);
    *(short8*)(xb + i) = h;
  } else if (bid < 4096) {                // codebook -> bf16 + ||e||^2 (wave/row)
    const int w = tid >> 6, lane = tid & 63;
    const int row = (bid - 2048) * 4 + w;
    f32x4 v = *(const f32x4*)(cb + row * DIM + lane * 4);
    u16x4 h;
    h.x = f2b(v.x); h.y = f2b(v.y); h.z = f2b(v.z); h.w = f2b(v.w);
    *(u16x4*)(cbb + row * DIM + lane * 4) = h;
    float s = v.x * v.x + v.y * v.y + v.z * v.z + v.w * v.w;
    #pragma unroll
    for (int m = 1; m <= 32; m <<= 1) s += __shfl_xor(s, m);
    if (lane == 0) norms[row] = s;
  } else {                                // init argmin keys (max of positive keys)
    const int i = (bid - 4096) * 256 + tid;
    amin[i] = 0u;
  }
}

// ---------------- fused GEMM + argmin ----------------
// grid 1024: kb = bid&7 (8 chunks of 1024 codes, chunk<->XCD affinity),
// rb = bid>>3 (128 row blocks of 128 rows). 4 waves/block, 32 rows/wave
// (A = 64 VGPR -> stays register-resident; total ~110 VGPR -> 4 waves/SIMD).
// 4 blocks/CU (LDS 20 KB), 16 waves/CU. Codebook tiles (16 codes, 8 KB)
// double-buffered, staged cooperatively by all 4 waves via global_load_lds.
// ONE barrier per tile: vmcnt(0) proves own stage(t) landed; barrier proves
// everyone's stage(t) landed AND everyone's reads(t-1) are done; stage(t+1)
// issued right after the barrier stays in flight across the whole compute.
// LDS XOR-swizzle on 16B columns (both-sides, rule #21).
// Argmin via u32 key packing: maximize m = 0.5 - ||e||^2 + 2 x.e  (positive,
// in ~[0.42,0.58]); key = (m_bits & ~0x1FFF) | code; running v_max_u32.
#define STAGE(tt, B)                                                           \
  {                                                                            \
    const char* gsrc = (const char*)cbb + (size_t)(kbase + (tt)*16) * 512;     \
    _Pragma("unroll")                                                          \
    for (int i = 0; i < 2; ++i) {                                              \
      const int o = i * 4096 + w * 1024 + lane * 16;                           \
      const int crow = o >> 9;                                                 \
      const int gcol = ((o >> 4) & 31) ^ (crow & 7);                           \
      async16(gsrc + crow * 512 + gcol * 16, &ldsbuf[B][i * 4096 + w * 1024]); \
    }                                                                          \
  }

__global__ __launch_bounds__(256, 4) void vq_argmin(
    const unsigned short* __restrict__ xb, const unsigned short* __restrict__ cbb,
    const float* __restrict__ norms, unsigned* __restrict__ amin) {
  __shared__ __align__(16) char ldsbuf[2][8192];
  __shared__ __align__(16) float ldsbias[1024];
  const int tid = threadIdx.x;
  const int w = tid >> 6, lane = tid & 63;
  const int c = lane & 15, hi = lane >> 4;
  const int kb = blockIdx.x & 7;
  const int rb = blockIdx.x >> 3;
  const int kbase = kb * 1024;
  const int rowbase = rb * 128 + w * 32;

  // A fragments: 2 row-tiles x 8 k-chunks, 64 VGPRs -- resident for the loop
  short8 a[2][8];
  #pragma unroll
  for (int rt = 0; rt < 2; ++rt)
    #pragma unroll
    for (int d = 0; d < 8; ++d)
      a[rt][d] = *(const short8*)(xb + (size_t)(rowbase + rt * 16 + c) * DIM + d * 32 + hi * 8);

  // bias = 0.5 - ||e||^2 for this chunk, staged to LDS
  {
    f32x4 v = *(const f32x4*)(norms + kbase + tid * 4);
    f32x4 b;
    b.x = 0.5f - v.x; b.y = 0.5f - v.y; b.z = 0.5f - v.z; b.w = 0.5f - v.w;
    *(f32x4*)(ldsbias + tid * 4) = b;
  }

  STAGE(0, 0);

  unsigned kmax0[4] = {0u, 0u, 0u, 0u};
  unsigned kmax1[4] = {0u, 0u, 0u, 0u};
  unsigned code = (unsigned)(kbase + c);

  __syncthreads();   // full drain: A loads, bias ds_writes, stage(0) visible

  #pragma unroll 2
  for (int t = 0; t < 64; ++t) {
    asm volatile("s_waitcnt vmcnt(0)" ::: "memory");   // own stage(t) landed
    __builtin_amdgcn_s_barrier();                      // all stage(t) + all reads(t-1)
    __builtin_amdgcn_sched_barrier(0);
    if (t < 63) STAGE(t + 1, (t + 1) & 1);             // overwrite old buf, in flight

    const float bias = ldsbias[t * 16 + c];
    f32x4 acc0 = {0.f, 0.f, 0.f, 0.f}, acc1 = acc0;
    #pragma unroll
    for (int d = 0; d < 8; ++d) {
      const int col16 = (d * 4 + hi) ^ (c & 7);        // swizzled read
      short8 b = *(const short8*)(&ldsbuf[t & 1][c * 512 + col16 * 16]);
      acc0 = __builtin_amdgcn_mfma_f32_16x16x32_bf16(a[0][d], b, acc0, 0, 0, 0);
      acc1 = __builtin_amdgcn_mfma_f32_16x16x32_bf16(a[1][d], b, acc1, 0, 0, 0);
    }
    #pragma unroll
    for (int j = 0; j < 4; ++j) {
      unsigned k0 = (__float_as_uint(fmaf(2.0f, acc0[j], bias)) & 0xFFFFE000u) | code;
      kmax0[j] = kmax0[j] > k0 ? kmax0[j] : k0;
      unsigned k1 = (__float_as_uint(fmaf(2.0f, acc1[j], bias)) & 0xFFFFE000u) | code;
      kmax1[j] = kmax1[j] > k1 ? kmax1[j] : k1;
    }
    code += 16u;
  }

  // reduce max over the 16 c-lanes sharing each output row, then one atomic
  #pragma unroll
  for (int j = 0; j < 4; ++j) {
    unsigned k0 = kmax0[j], k1 = kmax1[j];
    #pragma unroll
    for (int m = 1; m <= 8; m <<= 1) {
      unsigned o0 = __shfl_xor(k0, m); k0 = k0 > o0 ? k0 : o0;
      unsigned o1 = __shfl_xor(k1, m); k1 = k1 > o1 ? k1 : o1;
    }
    if (c == 0) {
      const int row = rowbase + hi * 4 + j;
      atomicMax(&amin[row], k0);
      atomicMax(&amin[row + 16], k1);
    }
  }
}

// ---------------- gather + straight-through + loss partials ----------------
__global__ void vq_gather(const float* __restrict__ x, const float* __restrict__ cb,
                          const unsigned* __restrict__ amin,
                          float* __restrict__ out, float* __restrict__ partial) {
  __shared__ float wsum[4];
  const int tid = threadIdx.x;
  const int w = tid >> 6, lane = tid & 63;
  const int r = blockIdx.x * 4 + w;
  const int idx = (int)(amin[r] & 8191u);            // low 13 bits = argmin index
  const f32x4 q  = *(const f32x4*)(cb + (size_t)idx * DIM + lane * 4);
  const f32x4 xv = *(const f32x4*)(x + (size_t)r * DIM + lane * 4);
  f32x4 d = q - xv;
  *(f32x4*)(out + (size_t)r * DIM + lane * 4) = xv + d;  // straight-through value
  float s = d.x * d.x + d.y * d.y + d.z * d.z + d.w * d.w;
  #pragma unroll
  for (int m = 1; m <= 32; m <<= 1) s += __shfl_xor(s, m);
  if (lane == 0) wsum[w] = s;
  __syncthreads();
  if (tid == 0) partial[blockIdx.x] = wsum[0] + wsum[1] + wsum[2] + wsum[3];
}

__global__ void vq_finalize(const float* __restrict__ partial, float* __restrict__ out) {
  __shared__ float wsum[4];
  const int tid = threadIdx.x;
  float s = 0.0f;
  #pragma unroll
  for (int i = 0; i < 16; ++i) s += partial[i * 256 + tid];
  #pragma unroll
  for (int m = 1; m <= 32; m <<= 1) s += __shfl_xor(s, m);
  if ((tid & 63) == 0) wsum[tid >> 6] = s;
  __syncthreads();
  if (tid == 0)
    out[NELEM] = 1.25f * (wsum[0] + wsum[1] + wsum[2] + wsum[3]) * (1.0f / 4194304.0f);
}

extern "C" void kernel_launch(void* const* d_in, const int* in_sizes, int n_in,
                              void* d_out, int out_size, void* d_ws, size_t ws_size,
                              hipStream_t stream) {
  const float* x  = (const float*)d_in[0];
  const float* cb = (const float*)d_in[1];
  float* out = (float*)d_out;
  char* ws = (char*)d_ws;
  unsigned short* xb  = (unsigned short*)(ws + WS_X);
  unsigned short* cbb = (unsigned short*)(ws + WS_CB);
  float* norms = (float*)(ws + WS_NORM);
  unsigned* amin = (unsigned*)(ws + WS_AMIN);
  float* partial = (float*)(ws + WS_PART);

  vq_prep<<<4160, 256, 0, stream>>>(x, cb, xb, cbb, norms, amin);
  vq_argmin<<<1024, 256, 0, stream>>>(xb, cbb, norms, amin);
  vq_gather<<<4096, 256, 0, stream>>>(x, cb, amin, out, partial);
  vq_finalize<<<1, 256, 0, stream>>>(partial, out);
}